// Round 18
// baseline (632.748 us; speedup 1.0000x reference)
//
#include <hip/hip_runtime.h>
#include <hip/hip_bf16.h>

// SceneGraph head — Round 18.
// r17 post-mortem: mode-5 LDS epilogue reverted (conv writes are L3-absorbed
// in warm replay; barriers cost more). Real fix: sF bank = 4w only
// (c*1024, h*32 both ≡ 0 mod 32) -> 7 same-w lanes collide on every y-pass
// tap. Pad sF h-stride 32->36 floats: bank quad = (h+w) mod 8, spreads by p.

#define Bimg 8
#define Cch 256
#define HW 1024
#define CREL 384
#define CCAT 640
#define KFC 12544
#define STS 236
#define SFS 36      // sF h-stride (floats), ≡4 mod 32
#define SFC 1152    // sF c-stride = 32*SFS

typedef __hip_bfloat16 bf16;
typedef __attribute__((ext_vector_type(8))) short short8;
typedef __attribute__((ext_vector_type(4))) short short4_t;
typedef __attribute__((ext_vector_type(4))) float f32x4;

__device__ __forceinline__ float hat_int(float t) {
    t = fminf(1.f, fmaxf(-1.f, t));
    return (t < 0.f) ? 0.5f * (t + 1.f) * (t + 1.f) : 1.f - 0.5f * (1.f - t) * (1.f - t);
}
__device__ __forceinline__ float b2f(short s) {
    return __uint_as_float(((unsigned)(unsigned short)s) << 16);
}
__device__ __forceinline__ unsigned pack2bf(float a, float b) {
    bf16 ha = __float2bfloat16(a), hb = __float2bfloat16(b);
    return ((unsigned)(unsigned short)(*(short*)&hb) << 16) | (unsigned short)(*(short*)&ha);
}
__device__ __forceinline__ void u2pair(int u, int& oi, int& oj) {
    int ii = 0, base = 0;
    while (u >= base + 16 - ii) { base += 16 - ii; ii++; }
    oi = ii; oj = ii + (u - base);
}

// ---------------- merged weight prep ----------------
__global__ void prep_k(const float* __restrict__ Wc, const float* __restrict__ bc,
                       const float* __restrict__ Wr, const float* __restrict__ br,
                       bf16* __restrict__ Wcat, float* __restrict__ bcat,
                       const float* __restrict__ Wof, bf16* __restrict__ wof16,
                       const float* __restrict__ Wrf, bf16* __restrict__ wasao16,
                       bf16* __restrict__ wrfxyz16) {
    int bid = blockIdx.x, tid = threadIdx.x;
    if (bid < 640) {
        int t = bid * 256 + tid;
        int d = t >> 8, c = t & 255;
        Wcat[t] = __float2bfloat16((d < 256) ? Wc[d * 256 + c] : Wr[(d - 256) * 256 + c]);
        if (t < CCAT) bcat[t] = (t < 256) ? bc[t] : br[t - 256];
    } else if (bid < 1152) {
        int t = (bid - 640) * 256 + tid;
        wof16[t] = __float2bfloat16(Wof[t]);
    } else if (bid < 1664) {
        int t = (bid - 1152) * 256 + tid;
        int m = t >> 8, k = t & 255;
        wasao16[t] = __float2bfloat16((m < 256) ? Wrf[m * 896 + k] : Wrf[(m - 256) * 896 + 256 + k]);
    } else {
        int t = (bid - 1664) * 256 + tid;
        int d = t / 384, k = t - d * 384;
        wrfxyz16[t] = __float2bfloat16(Wrf[d * 896 + 512 + k]);
    }
}
// FC weight repack to pq-major k-layout
__global__ __launch_bounds__(256) void wfc_pack_k(const float* __restrict__ W, bf16* __restrict__ dst) {
    __shared__ float ld[64 * 50];
    int dout = blockIdx.y, d0 = blockIdx.x * 64;
    int tid = threadIdx.x;
    for (int e = tid; e < 64 * 49; e += 256) {
        int di = e / 49, pq = e - di * 49;
        ld[di * 50 + pq] = W[(size_t)dout * KFC + (d0 + di) * 49 + pq];
    }
    __syncthreads();
    for (int e = tid; e < 64 * 49; e += 256) {
        int pq = e >> 6, di = e & 63;
        if (pq < 49)
            dst[(size_t)dout * KFC + pq * 256 + d0 + di] = __float2bfloat16(ld[di * 50 + pq]);
    }
}

// ---------------- per-roi packed records + intersection maps ----------------
__global__ void axisw_k(const float* __restrict__ objects,
                        float* __restrict__ orec, float* __restrict__ urec,
                        float* __restrict__ crec, float* __restrict__ bimap) {
    int bid = blockIdx.x;
    float b0, b1, b2, b3;
    float* rec;
    const float *sbp = nullptr, *obp = nullptr;
    if (bid < 128) {
        b0 = objects[bid * 4]; b1 = objects[bid * 4 + 1];
        b2 = objects[bid * 4 + 2]; b3 = objects[bid * 4 + 3];
        rec = orec + (size_t)bid * 128;
    } else if (bid < 2176) {
        int u = bid - 128;
        int img = u >> 8, pair = u & 255, i = pair >> 4, j = pair & 15;
        sbp = objects + (img * 16 + i) * 4;
        obp = objects + (img * 16 + j) * 4;
        b0 = fminf(sbp[0], obp[0]); b1 = fminf(sbp[1], obp[1]);
        b2 = fmaxf(sbp[2], obp[2]); b3 = fmaxf(sbp[3], obp[3]);
        rec = urec + (size_t)(u) * 224;
    } else {
        b0 = 0.f; b1 = 0.f; b2 = 512.f; b3 = 512.f;
        rec = crec;
    }
    const float sc = 0.0625f;
    float lox = b0 * sc, bwx = (b2 * sc - lox) * (1.f / 7.f);
    float loy = b1 * sc, bwy = (b3 * sc - loy) * (1.f / 7.f);
    float ia = 1.f / fmaxf(bwx * bwy, 1e-8f);
    int tid = threadIdx.x;
    if (tid < 56) {
        int p = tid >> 3, k = tid & 7;
        {
            float st = loy + bwy * p, en = st + bwy;
            int h0 = min(max((int)floorf(st) - 1, 0), 24);
            rec[tid] = hat_int(en - (float)(h0 + k)) - hat_int(st - (float)(h0 + k));
            if (k == 0) ((int*)rec)[119 + p] = h0;
        }
        {
            float st = lox + bwx * p, en = st + bwx;
            int w0 = min(max((int)floorf(st) - 1, 0), 24);
            rec[56 + tid] = ia * (hat_int(en - (float)(w0 + k)) - hat_int(st - (float)(w0 + k)));
            if (k == 0) ((int*)rec)[112 + p] = w0;
        }
    }
    if (tid < 49) {
        int p = tid / 7, q = tid - p * 7;
        if (bid < 128) {
            float bw = 512.f / 7.f, bh = 512.f / 7.f;
            float gx0 = bw * q, gy0 = bh * p;
            float ox = fmaxf(fminf(gx0 + bw, b2) - fmaxf(gx0, b0), 0.f);
            float oy = fmaxf(fminf(gy0 + bh, b3) - fmaxf(gy0, b1), 0.f);
            bimap[bid * 49 + tid] = oy * ox / fmaxf(bw * bh, 1e-8f);
        } else if (bid < 2176) {
            float bw = (b2 - b0) * (1.f / 7.f), bh = (b3 - b1) * (1.f / 7.f);
            float gx0 = b0 + bw * q, gy0 = b1 + bh * p;
            float inv = 1.f / fmaxf(bw * bh, 1e-8f);
            float oxs = fmaxf(fminf(gx0 + bw, sbp[2]) - fmaxf(gx0, sbp[0]), 0.f);
            float oys = fmaxf(fminf(gy0 + bh, sbp[3]) - fmaxf(gy0, sbp[1]), 0.f);
            rec[126 + tid] = oys * oxs * inv;
            float oxo = fmaxf(fminf(gx0 + bw, obp[2]) - fmaxf(gx0, obp[0]), 0.f);
            float oyo = fmaxf(fminf(gy0 + bh, obp[3]) - fmaxf(gy0, obp[1]), 0.f);
            rec[175 + tid] = oyo * oxo * inv;
        }
    }
}

// input [b][c][hw] fp32 -> INT16 [(b*1024+hw)][c] bf16
__global__ __launch_bounds__(256) void int_t_k(const float* __restrict__ input, bf16* __restrict__ intp) {
    __shared__ float st[64][65];
    int hw0 = blockIdx.x * 64, c0 = blockIdx.y * 64, b = blockIdx.z;
    int tid = threadIdx.x;
#pragma unroll
    for (int i = 0; i < 16; i++) {
        int e = tid + i * 256;
        int c = e >> 6, hw = e & 63;
        st[c][hw] = input[(size_t)b * 262144 + (size_t)(c0 + c) * 1024 + hw0 + hw];
    }
    __syncthreads();
#pragma unroll
    for (int i = 0; i < 16; i++) {
        int e = tid + i * 256;
        int hw = e >> 6, c = e & 63;
        intp[((size_t)b * 1024 + hw0 + hw) * 256 + c0 + c] = __float2bfloat16(st[c][hw]);
    }
}

// ---------------- BM128xBN128 barrier-free MFMA GEMM ----------------
// Modes: 2: split-K [kz][N][M] f32; 3: Ct[n][m] bf16 (bias optional);
// 5: Ct[m][n] bf16 (direct); 6: mode3 + Ct2[r][pq*256+m] relu bf16
__global__ __launch_bounds__(256) void mfma_gemm_k(
    const bf16* __restrict__ A, int lda,
    const bf16* __restrict__ BT, int ldbt,
    int Ktiles, int splitk, int mode,
    float* __restrict__ Cf, int Mtot, int Ntot,
    const float* __restrict__ bias,
    bf16* __restrict__ Ct, int ldct, bf16* __restrict__ Ct2) {
    __shared__ float tr[32 * 132];
    const int tid = threadIdx.x;
    const int m0 = blockIdx.y * 128, n0 = blockIdx.x * 128;
    int kz = blockIdx.z;
    const int tp = (Ktiles + splitk - 1) / splitk;
    const int kt0 = kz * tp;
    const int kt1 = min(Ktiles, kt0 + tp);
    const int lane = tid & 63, wid = tid >> 6;
    const int wm = (wid >> 1) * 64, wn = (wid & 1) * 64;
    const int lrow = lane & 15, lk = (lane >> 4) * 8;
    f32x4 acc[4][4];
#pragma unroll
    for (int i = 0; i < 4; i++)
#pragma unroll
        for (int j = 0; j < 4; j++) acc[i][j] = (f32x4){0.f, 0.f, 0.f, 0.f};
    const bf16* pA = A + (size_t)(m0 + wm + lrow) * lda + lk;
    const bf16* pB = BT + (size_t)(n0 + wn + lrow) * ldbt + lk;
    short8 a_c[4], b_c[4];
    if (kt0 < kt1) {
#pragma unroll
        for (int f = 0; f < 4; f++) {
            a_c[f] = *(const short8*)(pA + (size_t)f * 16 * lda + (size_t)kt0 * 32);
            b_c[f] = *(const short8*)(pB + (size_t)f * 16 * ldbt + (size_t)kt0 * 32);
        }
    }
    for (int kt = kt0; kt < kt1; kt++) {
        short8 a_n[4], b_n[4];
        if (kt + 1 < kt1) {
#pragma unroll
            for (int f = 0; f < 4; f++) {
                a_n[f] = *(const short8*)(pA + (size_t)f * 16 * lda + (size_t)(kt + 1) * 32);
                b_n[f] = *(const short8*)(pB + (size_t)f * 16 * ldbt + (size_t)(kt + 1) * 32);
            }
        }
#pragma unroll
        for (int i = 0; i < 4; i++)
#pragma unroll
            for (int j = 0; j < 4; j++)
                acc[i][j] = __builtin_amdgcn_mfma_f32_16x16x32_bf16(a_c[i], b_c[j], acc[i][j], 0, 0, 0);
#pragma unroll
        for (int f = 0; f < 4; f++) { a_c[f] = a_n[f]; b_c[f] = b_n[f]; }
    }
    const int rbase = (lane >> 4) * 4, cf = lane & 15;
    if (mode == 5) {
#pragma unroll
        for (int i = 0; i < 4; i++)
#pragma unroll
            for (int reg = 0; reg < 4; reg++) {
                int m = m0 + wm + i * 16 + rbase + reg;
                float bv = bias[m];
#pragma unroll
                for (int j = 0; j < 4; j++) {
                    int n = n0 + wn + j * 16 + cf;
                    Ct[(size_t)m * ldct + n] = __float2bfloat16(acc[i][j][reg] + bv);
                }
            }
        return;
    }
#pragma unroll 1
    for (int ci = 0; ci < 4; ci++) {
        __syncthreads();
        if ((wid & 1) == (ci >> 1)) {
            int jj0 = (ci & 1) * 2;
#pragma unroll
            for (int jj = jj0; jj < jj0 + 2; jj++)
#pragma unroll
                for (int i = 0; i < 4; i++)
#pragma unroll
                    for (int reg = 0; reg < 4; reg++) {
                        int nl = (wn + jj * 16 + cf) - 32 * ci;
                        int ml = wm + i * 16 + rbase + reg;
                        tr[nl * 132 + ml] = acc[i][jj][reg];
                    }
        }
        __syncthreads();
        if (mode == 2) {
            float* P = Cf + (size_t)kz * Mtot * Ntot;
            for (int e = tid; e < 1024; e += 256) {
                int nl = e >> 5, mq = (e & 31) * 4;
                int n = n0 + 32 * ci + nl;
                *(f32x4*)&P[(size_t)n * Mtot + m0 + mq] = *(f32x4*)&tr[nl * 132 + mq];
            }
        } else {
            for (int e = tid; e < 2048; e += 256) {
                int nl = e >> 6, mq = (e & 63) * 2;
                int n = n0 + 32 * ci + nl;
                int m = m0 + mq;
                float v0 = tr[nl * 132 + mq] + (bias ? bias[m] : 0.f);
                float v1 = tr[nl * 132 + mq + 1] + (bias ? bias[m + 1] : 0.f);
                *(unsigned*)&Ct[(size_t)n * ldct + m] = pack2bf(v0, v1);
                if (mode == 6) {
                    int r = n / 49, pq = n - r * 49;
                    *(unsigned*)&Ct2[(size_t)r * KFC + pq * 256 + m] =
                        pack2bf(fmaxf(v0, 0.f), fmaxf(v1, 0.f));
                }
            }
        }
    }
}

// ---------------- BM256xBN64 MFMA GEMM (C1 mode 1, r-fc mode 2) ----------------
__global__ __launch_bounds__(256) void mfma_gemm256_k(
    const bf16* __restrict__ A, int lda,
    const bf16* __restrict__ BT, int ldbt, long zB,
    int Ktiles, int splitk, int mode,
    float* __restrict__ Cf, int Ntot,
    const float* __restrict__ bias,
    const bf16* __restrict__ ASAOT, int bimg0,
    bf16* __restrict__ Ct, long zC) {
    __shared__ float tr[16 * 260];
    const int tid = threadIdx.x;
    const int n0 = blockIdx.x * 64;
    int z = blockIdx.z;
    int kz = 0, bimg = bimg0;
    if (mode == 1) { BT += (size_t)z * zB; Ct += (size_t)z * zC; bimg = bimg0 + z; }
    else kz = z;
    const int tp = (Ktiles + splitk - 1) / splitk;
    const int kt0 = kz * tp;
    const int kt1 = min(Ktiles, kt0 + tp);
    const int lane = tid & 63, wid = tid >> 6;
    const int wm = wid * 64;
    const int lrow = lane & 15, lk = (lane >> 4) * 8;
    f32x4 acc[4][4];
#pragma unroll
    for (int i = 0; i < 4; i++)
#pragma unroll
        for (int j = 0; j < 4; j++) acc[i][j] = (f32x4){0.f, 0.f, 0.f, 0.f};
    const bf16* pA = A + (size_t)(wm + lrow) * lda + lk;
    const bf16* pB = (mode == 1)
        ? BT + (size_t)(lk >> 3) * 100352 + (size_t)(n0 + lrow) * 8
        : BT + (size_t)(n0 + lrow) * ldbt + lk;
    short8 a_c[4], b_c[4];
    if (kt0 < kt1) {
#pragma unroll
        for (int f = 0; f < 4; f++) {
            a_c[f] = *(const short8*)(pA + (size_t)f * 16 * lda + (size_t)kt0 * 32);
            b_c[f] = (mode == 1)
                ? *(const short8*)(pB + (size_t)kt0 * 4 * 100352 + f * 128)
                : *(const short8*)(pB + (size_t)f * 16 * ldbt + (size_t)kt0 * 32);
        }
    }
    for (int kt = kt0; kt < kt1; kt++) {
        short8 a_n[4], b_n[4];
        if (kt + 1 < kt1) {
#pragma unroll
            for (int f = 0; f < 4; f++) {
                a_n[f] = *(const short8*)(pA + (size_t)f * 16 * lda + (size_t)(kt + 1) * 32);
                b_n[f] = (mode == 1)
                    ? *(const short8*)(pB + (size_t)(kt + 1) * 4 * 100352 + f * 128)
                    : *(const short8*)(pB + (size_t)f * 16 * ldbt + (size_t)(kt + 1) * 32);
            }
        }
#pragma unroll
        for (int i = 0; i < 4; i++)
#pragma unroll
            for (int j = 0; j < 4; j++)
                acc[i][j] = __builtin_amdgcn_mfma_f32_16x16x32_bf16(a_c[i], b_c[j], acc[i][j], 0, 0, 0);
#pragma unroll
        for (int f = 0; f < 4; f++) { a_c[f] = a_n[f]; b_c[f] = b_n[f]; }
    }
    const int rbase = (lane >> 4) * 4, cf = lane & 15;
#pragma unroll 1
    for (int ci = 0; ci < 4; ci++) {
        __syncthreads();
#pragma unroll
        for (int i = 0; i < 4; i++)
#pragma unroll
            for (int reg = 0; reg < 4; reg++)
                tr[cf * 260 + wm + i * 16 + rbase + reg] = acc[i][ci][reg];
        __syncthreads();
        if (mode == 2) {
            float* P = Cf + (size_t)kz * 256 * Ntot;
            for (int e = tid; e < 1024; e += 256) {
                int nl = e >> 6, mq = (e & 63) * 4;
                int n = n0 + 16 * ci + nl;
                *(f32x4*)&P[(size_t)n * 256 + mq] = *(f32x4*)&tr[nl * 260 + mq];
            }
        } else {  // mode 1
            for (int e = tid; e < 512; e += 256) {
                int nl = e >> 5, mq = (e & 31) * 8;
                int n = n0 + 16 * ci + nl;
                int r = n / 49, pq = n - r * 49;
                int ii = r >> 4, jj2 = r & 15;
                const bf16* as = &ASAOT[((size_t)bimg * 784 + ii * 49 + pq) * 512 + mq];
                const bf16* ao = &ASAOT[((size_t)bimg * 784 + jj2 * 49 + pq) * 512 + 256 + mq];
                short8 pk;
#pragma unroll
                for (int u = 0; u < 8; u++) {
                    float v = tr[nl * 260 + mq + u] + bias[mq + u]
                            + b2f(*(const short*)&as[u]) + b2f(*(const short*)&ao[u]);
                    bf16 h = __float2bfloat16(fmaxf(v, 0.f));
                    pk[u] = *(short*)&h;
                }
                *(short8*)&Ct[(size_t)r * KFC + pq * 256 + mq] = pk;
            }
        }
    }
}

// ---------------- obj pooling: input fp32 -> OBJINT ch [0,256) ----------------
__global__ __launch_bounds__(256) void objpool_k(
    const float* __restrict__ input, const float* __restrict__ orec,
    bf16* __restrict__ objint) {
    int cg = blockIdx.x;
    int b = blockIdx.y;
    __shared__ float sF[8 * SFC];
    __shared__ float sT[2][1888];
    __shared__ float wb[2][128];
    int tid = threadIdx.x;
    const float* feat = input + (size_t)b * (Cch * HW) + (size_t)cg * 8 * HW;
    for (int e4 = tid; e4 < 2048; e4 += 256) {
        int ch = e4 >> 8, rem = e4 & 255, h = rem >> 3, w4g = rem & 7;
        f32x4 v = *(const f32x4*)&feat[ch * 1024 + rem * 4];
        *(f32x4*)&sF[ch * SFC + h * SFS + w4g * 4] = v;
    }
    const float* rb = orec + (size_t)b * 16 * 128;
    if (tid < 126) wb[0][tid] = rb[tid];
    int t1v = tid + 256;
    int c0 = tid / 56, r0 = tid - c0 * 56, p0 = r0 >> 3, w40 = r0 & 7;
    int c1 = t1v / 56, r1 = t1v - c1 * 56, p1 = r1 >> 3, w41 = r1 & 7;
    bool has1 = (t1v < 448);
    int sf0 = c0 * SFC + w40 * 4, st0 = c0 * STS + p0 * 32 + w40 * 4;
    int sf1 = c1 * SFC + w41 * 4, st1 = c1 * STS + p1 * 32 + w41 * 4;
    int xpq0 = tid >> 3, xc = tid & 7;
    int xp0 = xpq0 / 7, xq0 = xpq0 - xp0 * 7;
    int xpq1 = xpq0 + 32;
    int xp1 = xpq1 / 7, xq1 = xpq1 - xp1 * 7;
    bool xv1 = (xpq1 < 49);
    __syncthreads();
    for (int r2 = 0; r2 < 16; r2++) {
        const float* wc_ = wb[r2 & 1];
        float* stbuf = sT[r2 & 1];
        float pre;
        bool pf = (r2 < 15) && (tid < 126);
        if (pf) pre = rb[(r2 + 1) * 128 + tid];
        {
            int h0 = ((const int*)wc_)[119 + p0];
            const f32x4* f = (const f32x4*)&sF[sf0 + h0 * SFS];
            f32x4 wya = *(const f32x4*)&wc_[p0 * 8];
            f32x4 wyb = *(const f32x4*)&wc_[p0 * 8 + 4];
            f32x4 a = f[0] * wya[0] + f[9] * wya[1] + f[18] * wya[2] + f[27] * wya[3]
                    + f[36] * wyb[0] + f[45] * wyb[1] + f[54] * wyb[2] + f[63] * wyb[3];
            *(f32x4*)&stbuf[st0] = a;
        }
        if (has1) {
            int h0 = ((const int*)wc_)[119 + p1];
            const f32x4* f = (const f32x4*)&sF[sf1 + h0 * SFS];
            f32x4 wya = *(const f32x4*)&wc_[p1 * 8];
            f32x4 wyb = *(const f32x4*)&wc_[p1 * 8 + 4];
            f32x4 a = f[0] * wya[0] + f[9] * wya[1] + f[18] * wya[2] + f[27] * wya[3]
                    + f[36] * wyb[0] + f[45] * wyb[1] + f[54] * wyb[2] + f[63] * wyb[3];
            *(f32x4*)&stbuf[st1] = a;
        }
        f32x4 xwa0 = *(const f32x4*)&wc_[56 + xq0 * 8];
        f32x4 xwb0 = *(const f32x4*)&wc_[56 + xq0 * 8 + 4];
        int w0i0 = ((const int*)wc_)[112 + xq0];
        f32x4 xwa1 = {0, 0, 0, 0}, xwb1 = {0, 0, 0, 0};
        int w0i1 = 0;
        if (xv1) {
            xwa1 = *(const f32x4*)&wc_[56 + xq1 * 8];
            xwb1 = *(const f32x4*)&wc_[56 + xq1 * 8 + 4];
            w0i1 = ((const int*)wc_)[112 + xq1];
        }
        if (pf) wb[1 - (r2 & 1)][tid] = pre;
        __syncthreads();
        {
            bf16* orow = objint + ((size_t)b * 784 + (size_t)r2 * 49) * 512 + cg * 8 + xc;
            {
                const float* t = &stbuf[xc * STS + xp0 * 32 + w0i0];
                float s = t[0] * xwa0[0] + t[1] * xwa0[1] + t[2] * xwa0[2] + t[3] * xwa0[3]
                        + t[4] * xwb0[0] + t[5] * xwb0[1] + t[6] * xwb0[2] + t[7] * xwb0[3];
                orow[(size_t)xpq0 * 512] = __float2bfloat16(s);
            }
            if (xv1) {
                const float* t = &stbuf[xc * STS + xp1 * 32 + w0i1];
                float s = t[0] * xwa1[0] + t[1] * xwa1[1] + t[2] * xwa1[2] + t[3] * xwa1[3]
                        + t[4] * xwb1[0] + t[5] * xwb1[1] + t[6] * xwb1[2] + t[7] * xwb1[3];
                orow[(size_t)xpq1 * 512] = __float2bfloat16(s);
            }
        }
    }
}

// ---------------- ctx pooling + objin fill fused ----------------
__global__ __launch_bounds__(256) void ctxobjin_k(
    const bf16* __restrict__ ctxrelb, const float* __restrict__ crec,
    const float* __restrict__ bimap, bf16* __restrict__ objint) {
    int cg = blockIdx.x;
    int b = blockIdx.y;
    __shared__ float sF[8 * SFC];
    __shared__ float sT[1888];
    __shared__ float wc_[128];
    __shared__ float sBI[784];
    int tid = threadIdx.x;
    for (int e4 = tid; e4 < 2048; e4 += 256) {
        int ch = e4 >> 8, rem = e4 & 255, h = rem >> 3, w4g = rem & 7;
        short4_t v = *(const short4_t*)&ctxrelb[(size_t)(cg * 8 + ch) * 8192 + b * 1024 + rem * 4];
        f32x4 fv = {b2f(v[0]), b2f(v[1]), b2f(v[2]), b2f(v[3])};
        *(f32x4*)&sF[ch * SFC + h * SFS + w4g * 4] = fv;
    }
    if (tid < 126) wc_[tid] = crec[tid];
    for (int e = tid; e < 784; e += 256) sBI[e] = bimap[b * 784 + e];
    __syncthreads();
    for (int tt = tid; tt < 448; tt += 256) {
        int c = tt / 56, r = tt - c * 56, p = r >> 3, w4 = r & 7;
        int h0 = ((const int*)wc_)[119 + p];
        const f32x4* f = (const f32x4*)&sF[c * SFC + w4 * 4 + h0 * SFS];
        f32x4 wya = *(const f32x4*)&wc_[p * 8];
        f32x4 wyb = *(const f32x4*)&wc_[p * 8 + 4];
        f32x4 a = f[0] * wya[0] + f[9] * wya[1] + f[18] * wya[2] + f[27] * wya[3]
                + f[36] * wyb[0] + f[45] * wyb[1] + f[54] * wyb[2] + f[63] * wyb[3];
        *(f32x4*)&sT[c * STS + p * 32 + w4 * 4] = a;
    }
    __syncthreads();
    bool scale = (cg >= 16);
    for (int e = tid; e < 392; e += 256) {
        int pq = e >> 3, c = e & 7;
        int p = pq / 7, q = pq - p * 7;
        int w0i = ((const int*)wc_)[112 + q];
        const float* t = &sT[c * STS + p * 32 + w0i];
        const f32x4* wx4 = (const f32x4*)&wc_[56 + q * 8];
        f32x4 a = wx4[0], b2 = wx4[1];
        float s = t[0] * a[0] + t[1] * a[1] + t[2] * a[2] + t[3] * a[3]
                + t[4] * b2[0] + t[5] * b2[1] + t[6] * b2[2] + t[7] * b2[3];
        int j = cg * 8 + c;
        bf16* orow = objint + ((size_t)b * 784 + pq) * 512 + 256 + j;
#pragma unroll
        for (int r = 0; r < 16; r++) {
            float m = scale ? sBI[r * 49 + pq] : 1.f;
            orow[(size_t)r * 49 * 512] = __float2bfloat16(s * m);
        }
    }
}

// ---------------- rel pooling: 136 unique unions, dual-row writes ----------------
__global__ __launch_bounds__(256) void relpool_k(
    const bf16* __restrict__ ctxrelb, const float* __restrict__ urec,
    bf16* __restrict__ mbt, int b0) {
    int cg = blockIdx.x;   // 0..47
    int rg = blockIdx.y;   // 0..16
    int zi = blockIdx.z;
    int b = b0 + zi;
    mbt += (size_t)zi * 4816896;
    __shared__ float sF[8 * SFC];
    __shared__ float sT[2][1888];
    __shared__ float wb[2][224];
    int tid = threadIdx.x;
    for (int e4 = tid; e4 < 2048; e4 += 256) {
        int ch = e4 >> 8, rem = e4 & 255, h = rem >> 3, w4g = rem & 7;
        short4_t v = *(const short4_t*)&ctxrelb[(size_t)(256 + cg * 8 + ch) * 8192 + b * 1024 + rem * 4];
        f32x4 fv = {b2f(v[0]), b2f(v[1]), b2f(v[2]), b2f(v[3])};
        *(f32x4*)&sF[ch * SFC + h * SFS + w4g * 4] = fv;
    }
    const float* rb = urec + (size_t)b * 256 * 224;
    {
        int i0, j0; u2pair(rg * 8, i0, j0);
        if (tid < 224) wb[0][tid] = rb[(size_t)(i0 * 16 + j0) * 224 + tid];
    }
    int t1v = tid + 256;
    int c0 = tid / 56, r0 = tid - c0 * 56, p0 = r0 >> 3, w40 = r0 & 7;
    int c1 = t1v / 56, r1 = t1v - c1 * 56, p1 = r1 >> 3, w41 = r1 & 7;
    bool has1 = (t1v < 448);
    int sf0 = c0 * SFC + w40 * 4, st0 = c0 * STS + p0 * 32 + w40 * 4;
    int sf1 = c1 * SFC + w41 * 4, st1 = c1 * STS + p1 * 32 + w41 * 4;
    int xpq0 = tid >> 3, xc = tid & 7;
    int xp0 = xpq0 / 7, xq0 = xpq0 - xp0 * 7;
    int xpq1 = xpq0 + 32;
    int xp1 = xpq1 / 7, xq1 = xpq1 - xp1 * 7;
    bool xv1 = (xpq1 < 49);
    int cglob = cg * 8 + xc;
    int mclass = (cglob >= 256) ? 2 : (cglob >= 128 ? 1 : 0);
    __syncthreads();
    for (int r2 = 0; r2 < 8; r2++) {
        const float* wc_ = wb[r2 & 1];
        float* stbuf = sT[r2 & 1];
        int pi, pj; u2pair(rg * 8 + r2, pi, pj);
        float pre;
        bool pf = (r2 < 7) && (tid < 224);
        if (pf) {
            int ni, nj; u2pair(rg * 8 + r2 + 1, ni, nj);
            pre = rb[(size_t)(ni * 16 + nj) * 224 + tid];
        }
        {
            int h0 = ((const int*)wc_)[119 + p0];
            const f32x4* f = (const f32x4*)&sF[sf0 + h0 * SFS];
            f32x4 wya = *(const f32x4*)&wc_[p0 * 8];
            f32x4 wyb = *(const f32x4*)&wc_[p0 * 8 + 4];
            f32x4 a = f[0] * wya[0] + f[9] * wya[1] + f[18] * wya[2] + f[27] * wya[3]
                    + f[36] * wyb[0] + f[45] * wyb[1] + f[54] * wyb[2] + f[63] * wyb[3];
            *(f32x4*)&stbuf[st0] = a;
        }
        if (has1) {
            int h0 = ((const int*)wc_)[119 + p1];
            const f32x4* f = (const f32x4*)&sF[sf1 + h0 * SFS];
            f32x4 wya = *(const f32x4*)&wc_[p1 * 8];
            f32x4 wyb = *(const f32x4*)&wc_[p1 * 8 + 4];
            f32x4 a = f[0] * wya[0] + f[9] * wya[1] + f[18] * wya[2] + f[27] * wya[3]
                    + f[36] * wyb[0] + f[45] * wyb[1] + f[54] * wyb[2] + f[63] * wyb[3];
            *(f32x4*)&stbuf[st1] = a;
        }
        f32x4 xwa0 = *(const f32x4*)&wc_[56 + xq0 * 8];
        f32x4 xwb0 = *(const f32x4*)&wc_[56 + xq0 * 8 + 4];
        int w0i0 = ((const int*)wc_)[112 + xq0];
        float si0 = wc_[126 + xpq0], oi0 = wc_[175 + xpq0];
        float mA0 = (mclass == 1) ? si0 : (mclass == 2 ? oi0 : 1.f);
        float mB0 = (mclass == 1) ? oi0 : (mclass == 2 ? si0 : 1.f);
        f32x4 xwa1 = {0, 0, 0, 0}, xwb1 = {0, 0, 0, 0};
        int w0i1 = 0;
        float mA1 = 1.f, mB1 = 1.f;
        if (xv1) {
            xwa1 = *(const f32x4*)&wc_[56 + xq1 * 8];
            xwb1 = *(const f32x4*)&wc_[56 + xq1 * 8 + 4];
            w0i1 = ((const int*)wc_)[112 + xq1];
            float si1 = wc_[126 + xpq1], oi1 = wc_[175 + xpq1];
            mA1 = (mclass == 1) ? si1 : (mclass == 2 ? oi1 : 1.f);
            mB1 = (mclass == 1) ? oi1 : (mclass == 2 ? si1 : 1.f);
        }
        if (pf) wb[1 - (r2 & 1)][tid] = pre;
        __syncthreads();
        {
            int rA = pi * 16 + pj, rB = pj * 16 + pi;
            bf16* baseA = mbt + (size_t)cg * 100352 + (size_t)rA * 392;
            bf16* baseB = mbt + (size_t)cg * 100352 + (size_t)rB * 392;
            bool dual = (pi != pj);
            {
                const float* t = &stbuf[xc * STS + xp0 * 32 + w0i0];
                float s = t[0] * xwa0[0] + t[1] * xwa0[1] + t[2] * xwa0[2] + t[3] * xwa0[3]
                        + t[4] * xwb0[0] + t[5] * xwb0[1] + t[6] * xwb0[2] + t[7] * xwb0[3];
                baseA[xpq0 * 8 + xc] = __float2bfloat16(s * mA0);
                if (dual) baseB[xpq0 * 8 + xc] = __float2bfloat16(s * mB0);
            }
            if (xv1) {
                const float* t = &stbuf[xc * STS + xp1 * 32 + w0i1];
                float s = t[0] * xwa1[0] + t[1] * xwa1[1] + t[2] * xwa1[2] + t[3] * xwa1[3]
                        + t[4] * xwb1[0] + t[5] * xwb1[1] + t[6] * xwb1[2] + t[7] * xwb1[3];
                baseA[xpq1 * 8 + xc] = __float2bfloat16(s * mA1);
                if (dual) baseB[xpq1 * 8 + xc] = __float2bfloat16(s * mB1);
            }
        }
    }
}

// ---------------- fused split-K reduce + bias + L2 norm + store ----------------
__global__ void redns_k(const float* __restrict__ Pd, const float* __restrict__ bias,
                        float* __restrict__ out, int N, int splitk, long outBase) {
    int vec = blockIdx.x, m = threadIdx.x;
    float s = bias[m];
    for (int z = 0; z < splitk; z++) s += Pd[(size_t)z * 256 * N + (size_t)vec * 256 + m];
    float ss = s * s;
    for (int o = 32; o > 0; o >>= 1) ss += __shfl_down(ss, o, 64);
    __shared__ float red[4];
    if ((m & 63) == 0) red[m >> 6] = ss;
    __syncthreads();
    float tot = red[0] + red[1] + red[2] + red[3];
    out[outBase + (size_t)vec * 256 + m] = s / sqrtf(tot);
}

extern "C" void kernel_launch(void* const* d_in, const int* in_sizes, int n_in,
                              void* d_out, int out_size, void* d_ws, size_t ws_size,
                              hipStream_t stream) {
    const float* input = (const float*)d_in[0];
    const float* objects = (const float*)d_in[1];
    const float* Wc = (const float*)d_in[3];
    const float* bc = (const float*)d_in[4];
    const float* Wr = (const float*)d_in[5];
    const float* br = (const float*)d_in[6];
    const float* Wof = (const float*)d_in[7];
    const float* bof = (const float*)d_in[8];
    const float* Wrf = (const float*)d_in[9];
    const float* brf = (const float*)d_in[10];
    const float* Wofc = (const float*)d_in[11];
    const float* bofc = (const float*)d_in[12];
    const float* Wrfc = (const float*)d_in[13];
    const float* brfc = (const float*)d_in[14];
    float* out = (float*)d_out;

    float* w = (float*)d_ws;
    bf16* WCAT16   = (bf16*)(w + 0);
    float* BCAT    = w + 81920;
    bf16* CTXRELB  = (bf16*)(w + 82560);
    float* OREC    = w + 2704000;
    float* UREC    = w + 2720384;
    float* CREC    = w + 3179136;
    float* BIMAP   = w + 3179264;
    bf16* ASAOT16  = (bf16*)(w + 3185536);
    bf16* WRFXYZ16 = (bf16*)(w + 4791168);
    bf16* WRFC16   = (bf16*)(w + 4840320);
    float* OVL     = w + 6445952;
    bf16* INT16    = (bf16*)(OVL + 0);
    bf16* WOF16    = (bf16*)(OVL + 1048576);
    bf16* WASAO16  = (bf16*)(OVL + 1114112);
    bf16* WOFC16   = (bf16*)(OVL + 1179648);
    bf16* OBJINT   = (bf16*)(OVL + 2785280);
    bf16* OBJFT    = (bf16*)(OVL + 4390912);
    bf16* XOT      = (bf16*)(OVL + 5193728);
    float* OPART   = OVL + 5996544;
    bf16* MBT4     = (bf16*)(OVL + 0);
    float* RPART   = OVL + 0;
    bf16* XBT4     = (bf16*)(OVL + 9633792);

    prep_k<<<dim3(2048), 256, 0, stream>>>(Wc, bc, Wr, br, WCAT16, BCAT,
                                           Wof, WOF16, Wrf, WASAO16, WRFXYZ16);
    wfc_pack_k<<<dim3(4, 256), 256, 0, stream>>>(Wrfc, WRFC16);
    wfc_pack_k<<<dim3(4, 256), 256, 0, stream>>>(Wofc, WOFC16);
    axisw_k<<<dim3(2177), 64, 0, stream>>>(objects, OREC, UREC, CREC, BIMAP);
    int_t_k<<<dim3(16, 4, 8), 256, 0, stream>>>(input, INT16);
    mfma_gemm_k<<<dim3(64, 5, 1), 256, 0, stream>>>(WCAT16, 256, INT16, 256, 8, 1, 5,
                                                    nullptr, 640, 8192, BCAT,
                                                    CTXRELB, 8192, nullptr);
    objpool_k<<<dim3(32, 8), 256, 0, stream>>>(input, OREC, OBJINT);
    ctxobjin_k<<<dim3(32, 8), 256, 0, stream>>>(CTXRELB, CREC, BIMAP, OBJINT);
    mfma_gemm_k<<<dim3(49, 2, 1), 256, 0, stream>>>(WOF16, 512, OBJINT, 512, 16, 1, 6,
                                                    nullptr, 256, 6272, bof,
                                                    OBJFT, 256, XOT);
    mfma_gemm_k<<<dim3(49, 4, 1), 256, 0, stream>>>(WASAO16, 256, OBJFT, 256, 8, 1, 3,
                                                    nullptr, 512, 6272, nullptr,
                                                    ASAOT16, 512, nullptr);
    mfma_gemm_k<<<dim3(1, 2, 56), 256, 0, stream>>>(WOFC16, KFC, XOT, KFC, 392, 56, 2,
                                                    OPART, 256, 128, nullptr,
                                                    nullptr, 0, nullptr);
    redns_k<<<dim3(128), 256, 0, stream>>>(OPART, bofc, out, 128, 56, 0L);

    for (int g = 0; g < 2; g++) {
        int b0 = g * 4;
        relpool_k<<<dim3(48, 17, 4), 256, 0, stream>>>(CTXRELB, UREC, MBT4, b0);
        mfma_gemm256_k<<<dim3(196, 1, 4), 256, 0, stream>>>(WRFXYZ16, 384, MBT4, 384, 4816896L,
                                                            12, 1, 1,
                                                            nullptr, KFC, brf,
                                                            ASAOT16, b0, XBT4, 3211264L);
        mfma_gemm256_k<<<dim3(16, 1, 24), 256, 0, stream>>>(WRFC16, KFC, XBT4, KFC, 0L,
                                                            392, 24, 2,
                                                            RPART, 1024, nullptr,
                                                            nullptr, 0, nullptr, 0L);
        redns_k<<<dim3(1024), 256, 0, stream>>>(RPART, brfc, out, 1024, 24,
                                                32768L + (long)g * 262144L);
    }
}

// Round 19
// 617.784 us; speedup vs baseline: 1.0242x; 1.0242x over previous
//
#include <hip/hip_runtime.h>
#include <hip/hip_bf16.h>

// SceneGraph head — Round 19 = Round 16 exactly (measured best: 618.98 us).
// r17 (mode-5 LDS epilogue) and r18 (sF pad-36) both regressed; reverted.
// Final structure: bf16 MFMA everywhere (barrier-free 128x128 + BM256xBN64),
// symmetric-union dedup relpool (136 unique unions, dual-row writes),
// coalesced MBT4 [cg][r][pq][8] layout, fused epilogues, 2x4-image batching.

#define Bimg 8
#define Cch 256
#define HW 1024
#define CREL 384
#define CCAT 640
#define KFC 12544
#define STS 236

typedef __hip_bfloat16 bf16;
typedef __attribute__((ext_vector_type(8))) short short8;
typedef __attribute__((ext_vector_type(4))) short short4_t;
typedef __attribute__((ext_vector_type(4))) float f32x4;

__device__ __forceinline__ float hat_int(float t) {
    t = fminf(1.f, fmaxf(-1.f, t));
    return (t < 0.f) ? 0.5f * (t + 1.f) * (t + 1.f) : 1.f - 0.5f * (1.f - t) * (1.f - t);
}
__device__ __forceinline__ float b2f(short s) {
    return __uint_as_float(((unsigned)(unsigned short)s) << 16);
}
__device__ __forceinline__ unsigned pack2bf(float a, float b) {
    bf16 ha = __float2bfloat16(a), hb = __float2bfloat16(b);
    return ((unsigned)(unsigned short)(*(short*)&hb) << 16) | (unsigned short)(*(short*)&ha);
}
// unique upper-triangle index u in [0,136) -> (i,j), i<=j
__device__ __forceinline__ void u2pair(int u, int& oi, int& oj) {
    int ii = 0, base = 0;
    while (u >= base + 16 - ii) { base += 16 - ii; ii++; }
    oi = ii; oj = ii + (u - base);
}

// ---------------- merged weight prep ----------------
__global__ void prep_k(const float* __restrict__ Wc, const float* __restrict__ bc,
                       const float* __restrict__ Wr, const float* __restrict__ br,
                       bf16* __restrict__ Wcat, float* __restrict__ bcat,
                       const float* __restrict__ Wof, bf16* __restrict__ wof16,
                       const float* __restrict__ Wrf, bf16* __restrict__ wasao16,
                       bf16* __restrict__ wrfxyz16) {
    int bid = blockIdx.x, tid = threadIdx.x;
    if (bid < 640) {
        int t = bid * 256 + tid;
        int d = t >> 8, c = t & 255;
        Wcat[t] = __float2bfloat16((d < 256) ? Wc[d * 256 + c] : Wr[(d - 256) * 256 + c]);
        if (t < CCAT) bcat[t] = (t < 256) ? bc[t] : br[t - 256];
    } else if (bid < 1152) {
        int t = (bid - 640) * 256 + tid;
        wof16[t] = __float2bfloat16(Wof[t]);
    } else if (bid < 1664) {
        int t = (bid - 1152) * 256 + tid;
        int m = t >> 8, k = t & 255;
        wasao16[t] = __float2bfloat16((m < 256) ? Wrf[m * 896 + k] : Wrf[(m - 256) * 896 + 256 + k]);
    } else {
        int t = (bid - 1664) * 256 + tid;
        int d = t / 384, k = t - d * 384;
        wrfxyz16[t] = __float2bfloat16(Wrf[d * 896 + 512 + k]);
    }
}
// FC weight repack to pq-major k-layout
__global__ __launch_bounds__(256) void wfc_pack_k(const float* __restrict__ W, bf16* __restrict__ dst) {
    __shared__ float ld[64 * 50];
    int dout = blockIdx.y, d0 = blockIdx.x * 64;
    int tid = threadIdx.x;
    for (int e = tid; e < 64 * 49; e += 256) {
        int di = e / 49, pq = e - di * 49;
        ld[di * 50 + pq] = W[(size_t)dout * KFC + (d0 + di) * 49 + pq];
    }
    __syncthreads();
    for (int e = tid; e < 64 * 49; e += 256) {
        int pq = e >> 6, di = e & 63;
        if (pq < 49)
            dst[(size_t)dout * KFC + pq * 256 + d0 + di] = __float2bfloat16(ld[di * 50 + pq]);
    }
}

// ---------------- per-roi packed records + intersection maps ----------------
__global__ void axisw_k(const float* __restrict__ objects,
                        float* __restrict__ orec, float* __restrict__ urec,
                        float* __restrict__ crec, float* __restrict__ bimap) {
    int bid = blockIdx.x;
    float b0, b1, b2, b3;
    float* rec;
    const float *sbp = nullptr, *obp = nullptr;
    if (bid < 128) {
        b0 = objects[bid * 4]; b1 = objects[bid * 4 + 1];
        b2 = objects[bid * 4 + 2]; b3 = objects[bid * 4 + 3];
        rec = orec + (size_t)bid * 128;
    } else if (bid < 2176) {
        int u = bid - 128;
        int img = u >> 8, pair = u & 255, i = pair >> 4, j = pair & 15;
        sbp = objects + (img * 16 + i) * 4;
        obp = objects + (img * 16 + j) * 4;
        b0 = fminf(sbp[0], obp[0]); b1 = fminf(sbp[1], obp[1]);
        b2 = fmaxf(sbp[2], obp[2]); b3 = fmaxf(sbp[3], obp[3]);
        rec = urec + (size_t)(u) * 224;
    } else {
        b0 = 0.f; b1 = 0.f; b2 = 512.f; b3 = 512.f;
        rec = crec;
    }
    const float sc = 0.0625f;
    float lox = b0 * sc, bwx = (b2 * sc - lox) * (1.f / 7.f);
    float loy = b1 * sc, bwy = (b3 * sc - loy) * (1.f / 7.f);
    float ia = 1.f / fmaxf(bwx * bwy, 1e-8f);
    int tid = threadIdx.x;
    if (tid < 56) {
        int p = tid >> 3, k = tid & 7;
        {
            float st = loy + bwy * p, en = st + bwy;
            int h0 = min(max((int)floorf(st) - 1, 0), 24);
            rec[tid] = hat_int(en - (float)(h0 + k)) - hat_int(st - (float)(h0 + k));
            if (k == 0) ((int*)rec)[119 + p] = h0;
        }
        {
            float st = lox + bwx * p, en = st + bwx;
            int w0 = min(max((int)floorf(st) - 1, 0), 24);
            rec[56 + tid] = ia * (hat_int(en - (float)(w0 + k)) - hat_int(st - (float)(w0 + k)));
            if (k == 0) ((int*)rec)[112 + p] = w0;
        }
    }
    if (tid < 49) {
        int p = tid / 7, q = tid - p * 7;
        if (bid < 128) {
            float bw = 512.f / 7.f, bh = 512.f / 7.f;
            float gx0 = bw * q, gy0 = bh * p;
            float ox = fmaxf(fminf(gx0 + bw, b2) - fmaxf(gx0, b0), 0.f);
            float oy = fmaxf(fminf(gy0 + bh, b3) - fmaxf(gy0, b1), 0.f);
            bimap[bid * 49 + tid] = oy * ox / fmaxf(bw * bh, 1e-8f);
        } else if (bid < 2176) {
            float bw = (b2 - b0) * (1.f / 7.f), bh = (b3 - b1) * (1.f / 7.f);
            float gx0 = b0 + bw * q, gy0 = b1 + bh * p;
            float inv = 1.f / fmaxf(bw * bh, 1e-8f);
            float oxs = fmaxf(fminf(gx0 + bw, sbp[2]) - fmaxf(gx0, sbp[0]), 0.f);
            float oys = fmaxf(fminf(gy0 + bh, sbp[3]) - fmaxf(gy0, sbp[1]), 0.f);
            rec[126 + tid] = oys * oxs * inv;
            float oxo = fmaxf(fminf(gx0 + bw, obp[2]) - fmaxf(gx0, obp[0]), 0.f);
            float oyo = fmaxf(fminf(gy0 + bh, obp[3]) - fmaxf(gy0, obp[1]), 0.f);
            rec[175 + tid] = oyo * oxo * inv;
        }
    }
}

// input [b][c][hw] fp32 -> INT16 [(b*1024+hw)][c] bf16
__global__ __launch_bounds__(256) void int_t_k(const float* __restrict__ input, bf16* __restrict__ intp) {
    __shared__ float st[64][65];
    int hw0 = blockIdx.x * 64, c0 = blockIdx.y * 64, b = blockIdx.z;
    int tid = threadIdx.x;
#pragma unroll
    for (int i = 0; i < 16; i++) {
        int e = tid + i * 256;
        int c = e >> 6, hw = e & 63;
        st[c][hw] = input[(size_t)b * 262144 + (size_t)(c0 + c) * 1024 + hw0 + hw];
    }
    __syncthreads();
#pragma unroll
    for (int i = 0; i < 16; i++) {
        int e = tid + i * 256;
        int hw = e >> 6, c = e & 63;
        intp[((size_t)b * 1024 + hw0 + hw) * 256 + c0 + c] = __float2bfloat16(st[c][hw]);
    }
}

// ---------------- BM128xBN128 barrier-free MFMA GEMM ----------------
// Modes: 2: split-K [kz][N][M] f32; 3: Ct[n][m] bf16 (bias optional);
// 5: Ct[m][n] bf16; 6: mode3 + Ct2[r][pq*256+m] relu bf16
__global__ __launch_bounds__(256) void mfma_gemm_k(
    const bf16* __restrict__ A, int lda,
    const bf16* __restrict__ BT, int ldbt,
    int Ktiles, int splitk, int mode,
    float* __restrict__ Cf, int Mtot, int Ntot,
    const float* __restrict__ bias,
    bf16* __restrict__ Ct, int ldct, bf16* __restrict__ Ct2) {
    __shared__ float tr[32 * 132];
    const int tid = threadIdx.x;
    const int m0 = blockIdx.y * 128, n0 = blockIdx.x * 128;
    int kz = blockIdx.z;
    const int tp = (Ktiles + splitk - 1) / splitk;
    const int kt0 = kz * tp;
    const int kt1 = min(Ktiles, kt0 + tp);
    const int lane = tid & 63, wid = tid >> 6;
    const int wm = (wid >> 1) * 64, wn = (wid & 1) * 64;
    const int lrow = lane & 15, lk = (lane >> 4) * 8;
    f32x4 acc[4][4];
#pragma unroll
    for (int i = 0; i < 4; i++)
#pragma unroll
        for (int j = 0; j < 4; j++) acc[i][j] = (f32x4){0.f, 0.f, 0.f, 0.f};
    const bf16* pA = A + (size_t)(m0 + wm + lrow) * lda + lk;
    const bf16* pB = BT + (size_t)(n0 + wn + lrow) * ldbt + lk;
    short8 a_c[4], b_c[4];
    if (kt0 < kt1) {
#pragma unroll
        for (int f = 0; f < 4; f++) {
            a_c[f] = *(const short8*)(pA + (size_t)f * 16 * lda + (size_t)kt0 * 32);
            b_c[f] = *(const short8*)(pB + (size_t)f * 16 * ldbt + (size_t)kt0 * 32);
        }
    }
    for (int kt = kt0; kt < kt1; kt++) {
        short8 a_n[4], b_n[4];
        if (kt + 1 < kt1) {
#pragma unroll
            for (int f = 0; f < 4; f++) {
                a_n[f] = *(const short8*)(pA + (size_t)f * 16 * lda + (size_t)(kt + 1) * 32);
                b_n[f] = *(const short8*)(pB + (size_t)f * 16 * ldbt + (size_t)(kt + 1) * 32);
            }
        }
#pragma unroll
        for (int i = 0; i < 4; i++)
#pragma unroll
            for (int j = 0; j < 4; j++)
                acc[i][j] = __builtin_amdgcn_mfma_f32_16x16x32_bf16(a_c[i], b_c[j], acc[i][j], 0, 0, 0);
#pragma unroll
        for (int f = 0; f < 4; f++) { a_c[f] = a_n[f]; b_c[f] = b_n[f]; }
    }
    const int rbase = (lane >> 4) * 4, cf = lane & 15;
    if (mode == 5) {
#pragma unroll
        for (int i = 0; i < 4; i++)
#pragma unroll
            for (int reg = 0; reg < 4; reg++) {
                int m = m0 + wm + i * 16 + rbase + reg;
                float bv = bias[m];
#pragma unroll
                for (int j = 0; j < 4; j++) {
                    int n = n0 + wn + j * 16 + cf;
                    Ct[(size_t)m * ldct + n] = __float2bfloat16(acc[i][j][reg] + bv);
                }
            }
        return;
    }
#pragma unroll 1
    for (int ci = 0; ci < 4; ci++) {
        __syncthreads();
        if ((wid & 1) == (ci >> 1)) {
            int jj0 = (ci & 1) * 2;
#pragma unroll
            for (int jj = jj0; jj < jj0 + 2; jj++)
#pragma unroll
                for (int i = 0; i < 4; i++)
#pragma unroll
                    for (int reg = 0; reg < 4; reg++) {
                        int nl = (wn + jj * 16 + cf) - 32 * ci;
                        int ml = wm + i * 16 + rbase + reg;
                        tr[nl * 132 + ml] = acc[i][jj][reg];
                    }
        }
        __syncthreads();
        if (mode == 2) {
            float* P = Cf + (size_t)kz * Mtot * Ntot;
            for (int e = tid; e < 1024; e += 256) {
                int nl = e >> 5, mq = (e & 31) * 4;
                int n = n0 + 32 * ci + nl;
                *(f32x4*)&P[(size_t)n * Mtot + m0 + mq] = *(f32x4*)&tr[nl * 132 + mq];
            }
        } else {
            for (int e = tid; e < 2048; e += 256) {
                int nl = e >> 6, mq = (e & 63) * 2;
                int n = n0 + 32 * ci + nl;
                int m = m0 + mq;
                float v0 = tr[nl * 132 + mq] + (bias ? bias[m] : 0.f);
                float v1 = tr[nl * 132 + mq + 1] + (bias ? bias[m + 1] : 0.f);
                *(unsigned*)&Ct[(size_t)n * ldct + m] = pack2bf(v0, v1);
                if (mode == 6) {
                    int r = n / 49, pq = n - r * 49;
                    *(unsigned*)&Ct2[(size_t)r * KFC + pq * 256 + m] =
                        pack2bf(fmaxf(v0, 0.f), fmaxf(v1, 0.f));
                }
            }
        }
    }
}

// ---------------- BM256xBN64 MFMA GEMM (C1 mode 1, r-fc mode 2) ----------------
// mode 1: B in per-image [cg][n(r*49+pq)][8] layout (coalesced relpool writes);
//         XBT = relu(acc + bias + AS + AO) bf16, pq-major k, z = image
// mode 2: B in [n][k] layout; split-K partials [kz][Ntot][256] f32, z = kz
__global__ __launch_bounds__(256) void mfma_gemm256_k(
    const bf16* __restrict__ A, int lda,
    const bf16* __restrict__ BT, int ldbt, long zB,
    int Ktiles, int splitk, int mode,
    float* __restrict__ Cf, int Ntot,
    const float* __restrict__ bias,
    const bf16* __restrict__ ASAOT, int bimg0,
    bf16* __restrict__ Ct, long zC) {
    __shared__ float tr[16 * 260];
    const int tid = threadIdx.x;
    const int n0 = blockIdx.x * 64;
    int z = blockIdx.z;
    int kz = 0, bimg = bimg0;
    if (mode == 1) { BT += (size_t)z * zB; Ct += (size_t)z * zC; bimg = bimg0 + z; }
    else kz = z;
    const int tp = (Ktiles + splitk - 1) / splitk;
    const int kt0 = kz * tp;
    const int kt1 = min(Ktiles, kt0 + tp);
    const int lane = tid & 63, wid = tid >> 6;
    const int wm = wid * 64;
    const int lrow = lane & 15, lk = (lane >> 4) * 8;
    f32x4 acc[4][4];
#pragma unroll
    for (int i = 0; i < 4; i++)
#pragma unroll
        for (int j = 0; j < 4; j++) acc[i][j] = (f32x4){0.f, 0.f, 0.f, 0.f};
    const bf16* pA = A + (size_t)(wm + lrow) * lda + lk;
    const bf16* pB = (mode == 1)
        ? BT + (size_t)(lk >> 3) * 100352 + (size_t)(n0 + lrow) * 8
        : BT + (size_t)(n0 + lrow) * ldbt + lk;
    short8 a_c[4], b_c[4];
    if (kt0 < kt1) {
#pragma unroll
        for (int f = 0; f < 4; f++) {
            a_c[f] = *(const short8*)(pA + (size_t)f * 16 * lda + (size_t)kt0 * 32);
            b_c[f] = (mode == 1)
                ? *(const short8*)(pB + (size_t)kt0 * 4 * 100352 + f * 128)
                : *(const short8*)(pB + (size_t)f * 16 * ldbt + (size_t)kt0 * 32);
        }
    }
    for (int kt = kt0; kt < kt1; kt++) {
        short8 a_n[4], b_n[4];
        if (kt + 1 < kt1) {
#pragma unroll
            for (int f = 0; f < 4; f++) {
                a_n[f] = *(const short8*)(pA + (size_t)f * 16 * lda + (size_t)(kt + 1) * 32);
                b_n[f] = (mode == 1)
                    ? *(const short8*)(pB + (size_t)(kt + 1) * 4 * 100352 + f * 128)
                    : *(const short8*)(pB + (size_t)f * 16 * ldbt + (size_t)(kt + 1) * 32);
            }
        }
#pragma unroll
        for (int i = 0; i < 4; i++)
#pragma unroll
            for (int j = 0; j < 4; j++)
                acc[i][j] = __builtin_amdgcn_mfma_f32_16x16x32_bf16(a_c[i], b_c[j], acc[i][j], 0, 0, 0);
#pragma unroll
        for (int f = 0; f < 4; f++) { a_c[f] = a_n[f]; b_c[f] = b_n[f]; }
    }
    const int rbase = (lane >> 4) * 4, cf = lane & 15;
#pragma unroll 1
    for (int ci = 0; ci < 4; ci++) {
        __syncthreads();
#pragma unroll
        for (int i = 0; i < 4; i++)
#pragma unroll
            for (int reg = 0; reg < 4; reg++)
                tr[cf * 260 + wm + i * 16 + rbase + reg] = acc[i][ci][reg];
        __syncthreads();
        if (mode == 2) {
            float* P = Cf + (size_t)kz * 256 * Ntot;
            for (int e = tid; e < 1024; e += 256) {
                int nl = e >> 6, mq = (e & 63) * 4;
                int n = n0 + 16 * ci + nl;
                *(f32x4*)&P[(size_t)n * 256 + mq] = *(f32x4*)&tr[nl * 260 + mq];
            }
        } else {  // mode 1
            for (int e = tid; e < 512; e += 256) {
                int nl = e >> 5, mq = (e & 31) * 8;
                int n = n0 + 16 * ci + nl;
                int r = n / 49, pq = n - r * 49;
                int ii = r >> 4, jj2 = r & 15;
                const bf16* as = &ASAOT[((size_t)bimg * 784 + ii * 49 + pq) * 512 + mq];
                const bf16* ao = &ASAOT[((size_t)bimg * 784 + jj2 * 49 + pq) * 512 + 256 + mq];
                short8 pk;
#pragma unroll
                for (int u = 0; u < 8; u++) {
                    float v = tr[nl * 260 + mq + u] + bias[mq + u]
                            + b2f(*(const short*)&as[u]) + b2f(*(const short*)&ao[u]);
                    bf16 h = __float2bfloat16(fmaxf(v, 0.f));
                    pk[u] = *(short*)&h;
                }
                *(short8*)&Ct[(size_t)r * KFC + pq * 256 + mq] = pk;
            }
        }
    }
}

// ---------------- obj pooling: input fp32 -> OBJINT ch [0,256) ----------------
__global__ __launch_bounds__(256) void objpool_k(
    const float* __restrict__ input, const float* __restrict__ orec,
    bf16* __restrict__ objint) {
    int cg = blockIdx.x;
    int b = blockIdx.y;
    __shared__ float sF[8192];
    __shared__ float sT[2][1888];
    __shared__ float wb[2][128];
    int tid = threadIdx.x;
    const float* feat = input + (size_t)b * (Cch * HW) + (size_t)cg * 8 * HW;
    for (int e4 = tid; e4 < 2048; e4 += 256)
        *(f32x4*)&sF[e4 * 4] = *(const f32x4*)&feat[e4 * 4];
    const float* rb = orec + (size_t)b * 16 * 128;
    if (tid < 126) wb[0][tid] = rb[tid];
    int t1v = tid + 256;
    int c0 = tid / 56, r0 = tid - c0 * 56, p0 = r0 >> 3, w40 = r0 & 7;
    int c1 = t1v / 56, r1 = t1v - c1 * 56, p1 = r1 >> 3, w41 = r1 & 7;
    bool has1 = (t1v < 448);
    int sf0 = c0 * 1024 + w40 * 4, st0 = c0 * STS + p0 * 32 + w40 * 4;
    int sf1 = c1 * 1024 + w41 * 4, st1 = c1 * STS + p1 * 32 + w41 * 4;
    int xpq0 = tid >> 3, xc = tid & 7;
    int xp0 = xpq0 / 7, xq0 = xpq0 - xp0 * 7;
    int xpq1 = xpq0 + 32;
    int xp1 = xpq1 / 7, xq1 = xpq1 - xp1 * 7;
    bool xv1 = (xpq1 < 49);
    __syncthreads();
    for (int r2 = 0; r2 < 16; r2++) {
        const float* wc_ = wb[r2 & 1];
        float* stbuf = sT[r2 & 1];
        float pre;
        bool pf = (r2 < 15) && (tid < 126);
        if (pf) pre = rb[(r2 + 1) * 128 + tid];
        {
            int h0 = ((const int*)wc_)[119 + p0];
            const f32x4* f = (const f32x4*)&sF[sf0 + h0 * 32];
            f32x4 wya = *(const f32x4*)&wc_[p0 * 8];
            f32x4 wyb = *(const f32x4*)&wc_[p0 * 8 + 4];
            f32x4 a = f[0] * wya[0] + f[8] * wya[1] + f[16] * wya[2] + f[24] * wya[3]
                    + f[32] * wyb[0] + f[40] * wyb[1] + f[48] * wyb[2] + f[56] * wyb[3];
            *(f32x4*)&stbuf[st0] = a;
        }
        if (has1) {
            int h0 = ((const int*)wc_)[119 + p1];
            const f32x4* f = (const f32x4*)&sF[sf1 + h0 * 32];
            f32x4 wya = *(const f32x4*)&wc_[p1 * 8];
            f32x4 wyb = *(const f32x4*)&wc_[p1 * 8 + 4];
            f32x4 a = f[0] * wya[0] + f[8] * wya[1] + f[16] * wya[2] + f[24] * wya[3]
                    + f[32] * wyb[0] + f[40] * wyb[1] + f[48] * wyb[2] + f[56] * wyb[3];
            *(f32x4*)&stbuf[st1] = a;
        }
        f32x4 xwa0 = *(const f32x4*)&wc_[56 + xq0 * 8];
        f32x4 xwb0 = *(const f32x4*)&wc_[56 + xq0 * 8 + 4];
        int w0i0 = ((const int*)wc_)[112 + xq0];
        f32x4 xwa1 = {0, 0, 0, 0}, xwb1 = {0, 0, 0, 0};
        int w0i1 = 0;
        if (xv1) {
            xwa1 = *(const f32x4*)&wc_[56 + xq1 * 8];
            xwb1 = *(const f32x4*)&wc_[56 + xq1 * 8 + 4];
            w0i1 = ((const int*)wc_)[112 + xq1];
        }
        if (pf) wb[1 - (r2 & 1)][tid] = pre;
        __syncthreads();
        {
            bf16* orow = objint + ((size_t)b * 784 + (size_t)r2 * 49) * 512 + cg * 8 + xc;
            {
                const float* t = &stbuf[xc * STS + xp0 * 32 + w0i0];
                float s = t[0] * xwa0[0] + t[1] * xwa0[1] + t[2] * xwa0[2] + t[3] * xwa0[3]
                        + t[4] * xwb0[0] + t[5] * xwb0[1] + t[6] * xwb0[2] + t[7] * xwb0[3];
                orow[(size_t)xpq0 * 512] = __float2bfloat16(s);
            }
            if (xv1) {
                const float* t = &stbuf[xc * STS + xp1 * 32 + w0i1];
                float s = t[0] * xwa1[0] + t[1] * xwa1[1] + t[2] * xwa1[2] + t[3] * xwa1[3]
                        + t[4] * xwb1[0] + t[5] * xwb1[1] + t[6] * xwb1[2] + t[7] * xwb1[3];
                orow[(size_t)xpq1 * 512] = __float2bfloat16(s);
            }
        }
    }
}

// ---------------- ctx pooling + objin fill fused ----------------
__global__ __launch_bounds__(256) void ctxobjin_k(
    const bf16* __restrict__ ctxrelb, const float* __restrict__ crec,
    const float* __restrict__ bimap, bf16* __restrict__ objint) {
    int cg = blockIdx.x;
    int b = blockIdx.y;
    __shared__ float sF[8192];
    __shared__ float sT[1888];
    __shared__ float wc_[128];
    __shared__ float sBI[784];
    int tid = threadIdx.x;
    for (int e4 = tid; e4 < 2048; e4 += 256) {
        short4_t v = *(const short4_t*)&ctxrelb[(size_t)(cg * 8 + (e4 >> 8)) * 8192 + b * 1024 + (e4 & 255) * 4];
        f32x4 fv = {b2f(v[0]), b2f(v[1]), b2f(v[2]), b2f(v[3])};
        *(f32x4*)&sF[e4 * 4] = fv;
    }
    if (tid < 126) wc_[tid] = crec[tid];
    for (int e = tid; e < 784; e += 256) sBI[e] = bimap[b * 784 + e];
    __syncthreads();
    for (int tt = tid; tt < 448; tt += 256) {
        int c = tt / 56, r = tt - c * 56, p = r >> 3, w4 = r & 7;
        int h0 = ((const int*)wc_)[119 + p];
        const f32x4* f = (const f32x4*)&sF[c * 1024 + w4 * 4 + h0 * 32];
        f32x4 wya = *(const f32x4*)&wc_[p * 8];
        f32x4 wyb = *(const f32x4*)&wc_[p * 8 + 4];
        f32x4 a = f[0] * wya[0] + f[8] * wya[1] + f[16] * wya[2] + f[24] * wya[3]
                + f[32] * wyb[0] + f[40] * wyb[1] + f[48] * wyb[2] + f[56] * wyb[3];
        *(f32x4*)&sT[c * STS + p * 32 + w4 * 4] = a;
    }
    __syncthreads();
    bool scale = (cg >= 16);
    for (int e = tid; e < 392; e += 256) {
        int pq = e >> 3, c = e & 7;
        int p = pq / 7, q = pq - p * 7;
        int w0i = ((const int*)wc_)[112 + q];
        const float* t = &sT[c * STS + p * 32 + w0i];
        const f32x4* wx4 = (const f32x4*)&wc_[56 + q * 8];
        f32x4 a = wx4[0], b2 = wx4[1];
        float s = t[0] * a[0] + t[1] * a[1] + t[2] * a[2] + t[3] * a[3]
                + t[4] * b2[0] + t[5] * b2[1] + t[6] * b2[2] + t[7] * b2[3];
        int j = cg * 8 + c;
        bf16* orow = objint + ((size_t)b * 784 + pq) * 512 + 256 + j;
#pragma unroll
        for (int r = 0; r < 16; r++) {
            float m = scale ? sBI[r * 49 + pq] : 1.f;
            orow[(size_t)r * 49 * 512] = __float2bfloat16(s * m);
        }
    }
}

// ---------------- rel pooling: 136 unique unions, dual-row writes ----------------
__global__ __launch_bounds__(256) void relpool_k(
    const bf16* __restrict__ ctxrelb, const float* __restrict__ urec,
    bf16* __restrict__ mbt, int b0) {
    int cg = blockIdx.x;   // 0..47
    int rg = blockIdx.y;   // 0..16 (17 groups of 8 unique pairs)
    int zi = blockIdx.z;
    int b = b0 + zi;
    mbt += (size_t)zi * 4816896;
    __shared__ float sF[8192];
    __shared__ float sT[2][1888];
    __shared__ float wb[2][224];
    int tid = threadIdx.x;
    for (int e4 = tid; e4 < 2048; e4 += 256) {
        short4_t v = *(const short4_t*)&ctxrelb[(size_t)(256 + cg * 8 + (e4 >> 8)) * 8192 + b * 1024 + (e4 & 255) * 4];
        f32x4 fv = {b2f(v[0]), b2f(v[1]), b2f(v[2]), b2f(v[3])};
        *(f32x4*)&sF[e4 * 4] = fv;
    }
    const float* rb = urec + (size_t)b * 256 * 224;
    {
        int i0, j0; u2pair(rg * 8, i0, j0);
        if (tid < 224) wb[0][tid] = rb[(size_t)(i0 * 16 + j0) * 224 + tid];
    }
    int t1v = tid + 256;
    int c0 = tid / 56, r0 = tid - c0 * 56, p0 = r0 >> 3, w40 = r0 & 7;
    int c1 = t1v / 56, r1 = t1v - c1 * 56, p1 = r1 >> 3, w41 = r1 & 7;
    bool has1 = (t1v < 448);
    int sf0 = c0 * 1024 + w40 * 4, st0 = c0 * STS + p0 * 32 + w40 * 4;
    int sf1 = c1 * 1024 + w41 * 4, st1 = c1 * STS + p1 * 32 + w41 * 4;
    int xpq0 = tid >> 3, xc = tid & 7;
    int xp0 = xpq0 / 7, xq0 = xpq0 - xp0 * 7;
    int xpq1 = xpq0 + 32;
    int xp1 = xpq1 / 7, xq1 = xpq1 - xp1 * 7;
    bool xv1 = (xpq1 < 49);
    int cglob = cg * 8 + xc;
    int mclass = (cglob >= 256) ? 2 : (cglob >= 128 ? 1 : 0);
    __syncthreads();
    for (int r2 = 0; r2 < 8; r2++) {
        const float* wc_ = wb[r2 & 1];
        float* stbuf = sT[r2 & 1];
        int pi, pj; u2pair(rg * 8 + r2, pi, pj);
        float pre;
        bool pf = (r2 < 7) && (tid < 224);
        if (pf) {
            int ni, nj; u2pair(rg * 8 + r2 + 1, ni, nj);
            pre = rb[(size_t)(ni * 16 + nj) * 224 + tid];
        }
        {   // y-pass task 0
            int h0 = ((const int*)wc_)[119 + p0];
            const f32x4* f = (const f32x4*)&sF[sf0 + h0 * 32];
            f32x4 wya = *(const f32x4*)&wc_[p0 * 8];
            f32x4 wyb = *(const f32x4*)&wc_[p0 * 8 + 4];
            f32x4 a = f[0] * wya[0] + f[8] * wya[1] + f[16] * wya[2] + f[24] * wya[3]
                    + f[32] * wyb[0] + f[40] * wyb[1] + f[48] * wyb[2] + f[56] * wyb[3];
            *(f32x4*)&stbuf[st0] = a;
        }
        if (has1) {  // y-pass task 1
            int h0 = ((const int*)wc_)[119 + p1];
            const f32x4* f = (const f32x4*)&sF[sf1 + h0 * 32];
            f32x4 wya = *(const f32x4*)&wc_[p1 * 8];
            f32x4 wyb = *(const f32x4*)&wc_[p1 * 8 + 4];
            f32x4 a = f[0] * wya[0] + f[8] * wya[1] + f[16] * wya[2] + f[24] * wya[3]
                    + f[32] * wyb[0] + f[40] * wyb[1] + f[48] * wyb[2] + f[56] * wyb[3];
            *(f32x4*)&stbuf[st1] = a;
        }
        // preload x weights + si/oi (both orderings) into registers
        f32x4 xwa0 = *(const f32x4*)&wc_[56 + xq0 * 8];
        f32x4 xwb0 = *(const f32x4*)&wc_[56 + xq0 * 8 + 4];
        int w0i0 = ((const int*)wc_)[112 + xq0];
        float si0 = wc_[126 + xpq0], oi0 = wc_[175 + xpq0];
        float mA0 = (mclass == 1) ? si0 : (mclass == 2 ? oi0 : 1.f);  // row (i,j)
        float mB0 = (mclass == 1) ? oi0 : (mclass == 2 ? si0 : 1.f);  // row (j,i)
        f32x4 xwa1 = {0, 0, 0, 0}, xwb1 = {0, 0, 0, 0};
        int w0i1 = 0;
        float mA1 = 1.f, mB1 = 1.f;
        if (xv1) {
            xwa1 = *(const f32x4*)&wc_[56 + xq1 * 8];
            xwb1 = *(const f32x4*)&wc_[56 + xq1 * 8 + 4];
            w0i1 = ((const int*)wc_)[112 + xq1];
            float si1 = wc_[126 + xpq1], oi1 = wc_[175 + xpq1];
            mA1 = (mclass == 1) ? si1 : (mclass == 2 ? oi1 : 1.f);
            mB1 = (mclass == 1) ? oi1 : (mclass == 2 ? si1 : 1.f);
        }
        if (pf) wb[1 - (r2 & 1)][tid] = pre;
        __syncthreads();
        {
            int rA = pi * 16 + pj, rB = pj * 16 + pi;
            bf16* baseA = mbt + (size_t)cg * 100352 + (size_t)rA * 392;
            bf16* baseB = mbt + (size_t)cg * 100352 + (size_t)rB * 392;
            bool dual = (pi != pj);
            {
                const float* t = &stbuf[xc * STS + xp0 * 32 + w0i0];
                float s = t[0] * xwa0[0] + t[1] * xwa0[1] + t[2] * xwa0[2] + t[3] * xwa0[3]
                        + t[4] * xwb0[0] + t[5] * xwb0[1] + t[6] * xwb0[2] + t[7] * xwb0[3];
                baseA[xpq0 * 8 + xc] = __float2bfloat16(s * mA0);
                if (dual) baseB[xpq0 * 8 + xc] = __float2bfloat16(s * mB0);
            }
            if (xv1) {
                const float* t = &stbuf[xc * STS + xp1 * 32 + w0i1];
                float s = t[0] * xwa1[0] + t[1] * xwa1[1] + t[2] * xwa1[2] + t[3] * xwa1[3]
                        + t[4] * xwb1[0] + t[5] * xwb1[1] + t[6] * xwb1[2] + t[7] * xwb1[3];
                baseA[xpq1 * 8 + xc] = __float2bfloat16(s * mA1);
                if (dual) baseB[xpq1 * 8 + xc] = __float2bfloat16(s * mB1);
            }
        }
    }
}

// ---------------- fused split-K reduce + bias + L2 norm + store ----------------
__global__ void redns_k(const float* __restrict__ Pd, const float* __restrict__ bias,
                        float* __restrict__ out, int N, int splitk, long outBase) {
    int vec = blockIdx.x, m = threadIdx.x;
    float s = bias[m];
    for (int z = 0; z < splitk; z++) s += Pd[(size_t)z * 256 * N + (size_t)vec * 256 + m];
    float ss = s * s;
    for (int o = 32; o > 0; o >>= 1) ss += __shfl_down(ss, o, 64);
    __shared__ float red[4];
    if ((m & 63) == 0) red[m >> 6] = ss;
    __syncthreads();
    float tot = red[0] + red[1] + red[2] + red[3];
    out[outBase + (size_t)vec * 256 + m] = s / sqrtf(tot);
}

extern "C" void kernel_launch(void* const* d_in, const int* in_sizes, int n_in,
                              void* d_out, int out_size, void* d_ws, size_t ws_size,
                              hipStream_t stream) {
    const float* input = (const float*)d_in[0];
    const float* objects = (const float*)d_in[1];
    const float* Wc = (const float*)d_in[3];
    const float* bc = (const float*)d_in[4];
    const float* Wr = (const float*)d_in[5];
    const float* br = (const float*)d_in[6];
    const float* Wof = (const float*)d_in[7];
    const float* bof = (const float*)d_in[8];
    const float* Wrf = (const float*)d_in[9];
    const float* brf = (const float*)d_in[10];
    const float* Wofc = (const float*)d_in[11];
    const float* bofc = (const float*)d_in[12];
    const float* Wrfc = (const float*)d_in[13];
    const float* brfc = (const float*)d_in[14];
    float* out = (float*)d_out;

    float* w = (float*)d_ws;
    bf16* WCAT16   = (bf16*)(w + 0);
    float* BCAT    = w + 81920;
    bf16* CTXRELB  = (bf16*)(w + 82560);
    float* OREC    = w + 2704000;
    float* UREC    = w + 2720384;
    float* CREC    = w + 3179136;
    float* BIMAP   = w + 3179264;
    bf16* ASAOT16  = (bf16*)(w + 3185536);
    bf16* WRFXYZ16 = (bf16*)(w + 4791168);
    bf16* WRFC16   = (bf16*)(w + 4840320);
    float* OVL     = w + 6445952;
    bf16* INT16    = (bf16*)(OVL + 0);
    bf16* WOF16    = (bf16*)(OVL + 1048576);
    bf16* WASAO16  = (bf16*)(OVL + 1114112);
    bf16* WOFC16   = (bf16*)(OVL + 1179648);
    bf16* OBJINT   = (bf16*)(OVL + 2785280);
    bf16* OBJFT    = (bf16*)(OVL + 4390912);
    bf16* XOT      = (bf16*)(OVL + 5193728);
    float* OPART   = OVL + 5996544;
    bf16* MBT4     = (bf16*)(OVL + 0);
    float* RPART   = OVL + 0;
    bf16* XBT4     = (bf16*)(OVL + 9633792);

    prep_k<<<dim3(2048), 256, 0, stream>>>(Wc, bc, Wr, br, WCAT16, BCAT,
                                           Wof, WOF16, Wrf, WASAO16, WRFXYZ16);
    wfc_pack_k<<<dim3(4, 256), 256, 0, stream>>>(Wrfc, WRFC16);
    wfc_pack_k<<<dim3(4, 256), 256, 0, stream>>>(Wofc, WOFC16);
    axisw_k<<<dim3(2177), 64, 0, stream>>>(objects, OREC, UREC, CREC, BIMAP);
    int_t_k<<<dim3(16, 4, 8), 256, 0, stream>>>(input, INT16);
    mfma_gemm_k<<<dim3(64, 5, 1), 256, 0, stream>>>(WCAT16, 256, INT16, 256, 8, 1, 5,
                                                    nullptr, 640, 8192, BCAT,
                                                    CTXRELB, 8192, nullptr);
    objpool_k<<<dim3(32, 8), 256, 0, stream>>>(input, OREC, OBJINT);
    ctxobjin_k<<<dim3(32, 8), 256, 0, stream>>>(CTXRELB, CREC, BIMAP, OBJINT);
    mfma_gemm_k<<<dim3(49, 2, 1), 256, 0, stream>>>(WOF16, 512, OBJINT, 512, 16, 1, 6,
                                                    nullptr, 256, 6272, bof,
                                                    OBJFT, 256, XOT);
    mfma_gemm_k<<<dim3(49, 4, 1), 256, 0, stream>>>(WASAO16, 256, OBJFT, 256, 8, 1, 3,
                                                    nullptr, 512, 6272, nullptr,
                                                    ASAOT16, 512, nullptr);
    mfma_gemm_k<<<dim3(1, 2, 56), 256, 0, stream>>>(WOFC16, KFC, XOT, KFC, 392, 56, 2,
                                                    OPART, 256, 128, nullptr,
                                                    nullptr, 0, nullptr);
    redns_k<<<dim3(128), 256, 0, stream>>>(OPART, bofc, out, 128, 56, 0L);

    for (int g = 0; g < 2; g++) {
        int b0 = g * 4;
        relpool_k<<<dim3(48, 17, 4), 256, 0, stream>>>(CTXRELB, UREC, MBT4, b0);
        mfma_gemm256_k<<<dim3(196, 1, 4), 256, 0, stream>>>(WRFXYZ16, 384, MBT4, 384, 4816896L,
                                                            12, 1, 1,
                                                            nullptr, KFC, brf,
                                                            ASAOT16, b0, XBT4, 3211264L);
        mfma_gemm256_k<<<dim3(16, 1, 24), 256, 0, stream>>>(WRFC16, KFC, XBT4, KFC, 0L,
                                                            392, 24, 2,
                                                            RPART, 1024, nullptr,
                                                            nullptr, 0, nullptr, 0L);
        redns_k<<<dim3(1024), 256, 0, stream>>>(RPART, brfc, out, 1024, 24,
                                                32768L + (long)g * 262144L);
    }
}